// Round 1
// baseline (446.256 us; speedup 1.0000x reference)
//
#include <hip/hip_runtime.h>
#include <math.h>

#define BB 64
#define LL 4096
#define DD 128
#define KMAXC 50
#define HH 64
#define PP 24
#define NM 49   // 2*P+1

// ---------------- Kernel 1: column partial sums over L ----------------
// grid (32, B), block 256. Each block sums 128 rows of x[b] into partial[b][c][d].
__global__ __launch_bounds__(256) void colsum_kernel(const float* __restrict__ x,
                                                     float* __restrict__ partial) {
    int tid = threadIdx.x;
    int dq  = tid & 31;    // float4 group along D (d = 4*dq..4*dq+3)
    int r   = tid >> 5;    // 0..7
    int c   = blockIdx.x;  // 0..31 (row chunk)
    int b   = blockIdx.y;
    const float4* xb = (const float4*)(x + (size_t)b * LL * DD);
    float4 s = make_float4(0.f, 0.f, 0.f, 0.f);
    int row0 = c * 128 + r;
#pragma unroll
    for (int i = 0; i < 16; ++i) {
        float4 v = xb[(size_t)(row0 + 8 * i) * 32 + dq];
        s.x += v.x; s.y += v.y; s.z += v.z; s.w += v.w;
    }
    __shared__ float4 sm[256];
    sm[tid] = s;
    __syncthreads();
    if (r == 0) {
        float4 t = sm[dq];
#pragma unroll
        for (int rr = 1; rr < 8; ++rr) {
            float4 v = sm[dq + 32 * rr];
            t.x += v.x; t.y += v.y; t.z += v.z; t.w += v.w;
        }
        float4* outp = (float4*)(partial + ((size_t)b * 32 + c) * DD);
        outp[dq] = t;
    }
}

// ---------------- Kernel 2: finalize mean, MLP -> k, softmax -> wo ----------------
// grid B, block 128 (one thread per d).
__global__ __launch_bounds__(128) void mlp_weights_kernel(
    const float* __restrict__ partial, const float* __restrict__ tw,
    const float* __restrict__ w1, const float* __restrict__ b1,
    const float* __restrict__ w2, const float* __restrict__ b2,
    float* __restrict__ wo, int* __restrict__ kout) {
    int b = blockIdx.x;
    int tid = threadIdx.x;  // d
    __shared__ float xg[DD];
    __shared__ int kp[2];
    float ssum = 0.f;
#pragma unroll 4
    for (int c = 0; c < 32; ++c) ssum += partial[((size_t)b * 32 + c) * DD + tid];
    xg[tid] = ssum * (1.0f / (float)LL);
    __syncthreads();

    // MLP: threads 0..63 each compute h[j] * w2[j]
    float hv = 0.f;
    if (tid < HH) {
        float acc = b1[tid];
#pragma unroll 8
        for (int d0 = 0; d0 < DD; ++d0) acc += xg[d0] * w1[d0 * HH + tid];
        hv = fmaxf(acc, 0.f) * w2[tid];
    }
    if (tid < 64) {  // wave 0 reduction across 64 lanes
#pragma unroll
        for (int off = 32; off > 0; off >>= 1) hv += __shfl_down(hv, off, 64);
        if (tid == 0) {
            float z = hv + b2[0];
            float logit = 1.0f / (1.0f + expf(-z));
            float kf = logit * (float)(KMAXC - 5) + 5.0f;
            int k = (int)rintf(kf);          // round-half-even, matches jnp.round
            k = min(max(k, 3), KMAXC);
            if ((k & 1) == 0) k -= 1;
            k = max(k, 3);
            kp[0] = k;
            kp[1] = k >> 1;
            kout[b] = k;
        }
    }
    __syncthreads();
    int k = kp[0], p = kp[1];

    // softmax over tw[d][0..k-1], scattered to wo[b][m][d] with zero padding
    const float* trow = tw + (size_t)tid * KMAXC;
    float mx = -1e30f;
    for (int j = 0; j < k; ++j) mx = fmaxf(mx, trow[j]);
    float s = 0.f;
    for (int j = 0; j < k; ++j) s += expf(trow[j] - mx);
    float inv = 1.0f / s;
    for (int m = 0; m < NM; ++m) {
        int j = m - PP + p;
        float w = (j >= 0 && j < k) ? expf(trow[j] - mx) * inv : 0.f;
        wo[((size_t)b * NM + m) * DD + tid] = w;
    }
}

// ---------------- Kernel 3: depth-wise conv + seasonal ----------------
// grid (L/32, B), block 256. Thread = (d, lsub); computes 16 consecutive l.
__global__ __launch_bounds__(256) void conv_kernel(
    const float* __restrict__ x, const float* __restrict__ wo,
    const int* __restrict__ kin, float* __restrict__ seasonal,
    float* __restrict__ trend) {
    int tid  = threadIdx.x;
    int d    = tid & 127;
    int lsub = tid >> 7;
    int b    = blockIdx.y;
    int l0   = blockIdx.x * 32 + lsub * 16;
    int k    = kin[b];
    int p    = k >> 1;

    const float* xb = x + (size_t)b * LL * DD + d;
    float xwin[64];
    int r0 = l0 - PP;
    if (r0 >= 0 && r0 + 63 < LL) {  // interior (wave-uniform branch)
#pragma unroll
        for (int i = 0; i < 64; ++i) xwin[i] = xb[(size_t)(r0 + i) * DD];
    } else {
#pragma unroll
        for (int i = 0; i < 64; ++i) {
            int r = r0 + i;
            r = r < 0 ? 0 : (r > LL - 1 ? LL - 1 : r);  // edge clamp (jnp.pad edge)
            xwin[i] = xb[(size_t)r * DD];
        }
    }

    const float* wb = wo + (size_t)b * NM * DD + d;
    float acc[16];
#pragma unroll
    for (int t = 0; t < 16; ++t) acc[t] = 0.f;

#pragma unroll
    for (int c = 0; c < 7; ++c) {
        int mlo = 7 * c;
        // wo[m]==0 outside [PP-p, PP+p]; skip fully-zero chunks (uniform per block)
        if (mlo + 6 < PP - p || mlo > PP + p) continue;
#pragma unroll
        for (int q = 0; q < 7; ++q) {
            int m = 7 * c + q;
            float w = wb[(size_t)m * DD];
#pragma unroll
            for (int t = 0; t < 16; ++t) acc[t] = fmaf(w, xwin[m + t], acc[t]);
        }
    }

    float* so = seasonal + ((size_t)b * LL + l0) * DD + d;
    float* to = trend + ((size_t)b * LL + l0) * DD + d;
#pragma unroll
    for (int t = 0; t < 16; ++t) {
        float tr = acc[t];
        to[(size_t)t * DD] = tr;
        so[(size_t)t * DD] = xwin[PP + t] - tr;  // xwin[PP+t] == x[l0+t] exactly
    }
}

extern "C" void kernel_launch(void* const* d_in, const int* in_sizes, int n_in,
                              void* d_out, int out_size, void* d_ws, size_t ws_size,
                              hipStream_t stream) {
    const float* x  = (const float*)d_in[0];
    const float* tw = (const float*)d_in[1];
    const float* w1 = (const float*)d_in[2];
    const float* b1 = (const float*)d_in[3];
    const float* w2 = (const float*)d_in[4];
    const float* b2 = (const float*)d_in[5];
    float* outp     = (float*)d_out;
    float* seasonal = outp;
    float* trend    = outp + (size_t)BB * LL * DD;

    float* partial = (float*)d_ws;                         // B*32*D floats = 1 MB
    float* wo      = partial + (size_t)BB * 32 * DD;       // B*49*D floats = 1.53 MB
    int*   kws     = (int*)(wo + (size_t)BB * NM * DD);    // B ints

    colsum_kernel<<<dim3(32, BB), 256, 0, stream>>>(x, partial);
    mlp_weights_kernel<<<BB, 128, 0, stream>>>(partial, tw, w1, b1, w2, b2, wo, kws);
    conv_kernel<<<dim3(LL / 32, BB), 256, 0, stream>>>(x, wo, kws, seasonal, trend);
}

// Round 2
// 415.462 us; speedup vs baseline: 1.0741x; 1.0741x over previous
//
#include <hip/hip_runtime.h>
#include <math.h>

#define BB 64
#define LL 4096
#define DD 128
#define KMAXC 50
#define HH 64
#define PP 24
#define NM 49   // 2*P+1

// ---------------- Kernel 1: column partial sums over L ----------------
// grid (32, B), block 256. Each block sums 128 rows of x[b] into partial[b][c][d].
__global__ __launch_bounds__(256) void colsum_kernel(const float* __restrict__ x,
                                                     float* __restrict__ partial) {
    int tid = threadIdx.x;
    int dq  = tid & 31;    // float4 group along D (d = 4*dq..4*dq+3)
    int r   = tid >> 5;    // 0..7
    int c   = blockIdx.x;  // 0..31 (row chunk)
    int b   = blockIdx.y;
    const float4* xb = (const float4*)(x + (size_t)b * LL * DD);
    float4 s = make_float4(0.f, 0.f, 0.f, 0.f);
    int row0 = c * 128 + r;
#pragma unroll
    for (int i = 0; i < 16; ++i) {
        float4 v = xb[(size_t)(row0 + 8 * i) * 32 + dq];
        s.x += v.x; s.y += v.y; s.z += v.z; s.w += v.w;
    }
    __shared__ float4 sm[256];
    sm[tid] = s;
    __syncthreads();
    if (r == 0) {
        float4 t = sm[dq];
#pragma unroll
        for (int rr = 1; rr < 8; ++rr) {
            float4 v = sm[dq + 32 * rr];
            t.x += v.x; t.y += v.y; t.z += v.z; t.w += v.w;
        }
        float4* outp = (float4*)(partial + ((size_t)b * 32 + c) * DD);
        outp[dq] = t;
    }
}

// ---------------- Kernel 2: finalize mean, MLP -> k, softmax -> wo ----------------
// grid B, block 128 (one thread per d).
__global__ __launch_bounds__(128) void mlp_weights_kernel(
    const float* __restrict__ partial, const float* __restrict__ tw,
    const float* __restrict__ w1, const float* __restrict__ b1,
    const float* __restrict__ w2, const float* __restrict__ b2,
    float* __restrict__ wo, int* __restrict__ kout) {
    int b = blockIdx.x;
    int tid = threadIdx.x;  // d
    __shared__ float xg[DD];
    __shared__ int kp[2];
    float ssum = 0.f;
#pragma unroll 4
    for (int c = 0; c < 32; ++c) ssum += partial[((size_t)b * 32 + c) * DD + tid];
    xg[tid] = ssum * (1.0f / (float)LL);
    __syncthreads();

    // MLP: threads 0..63 each compute h[j] * w2[j]
    float hv = 0.f;
    if (tid < HH) {
        float acc = b1[tid];
#pragma unroll 8
        for (int d0 = 0; d0 < DD; ++d0) acc += xg[d0] * w1[d0 * HH + tid];
        hv = fmaxf(acc, 0.f) * w2[tid];
    }
    if (tid < 64) {  // wave 0 reduction across 64 lanes
#pragma unroll
        for (int off = 32; off > 0; off >>= 1) hv += __shfl_down(hv, off, 64);
        if (tid == 0) {
            float z = hv + b2[0];
            float logit = 1.0f / (1.0f + expf(-z));
            float kf = logit * (float)(KMAXC - 5) + 5.0f;
            int k = (int)rintf(kf);          // round-half-even, matches jnp.round
            k = min(max(k, 3), KMAXC);
            if ((k & 1) == 0) k -= 1;
            k = max(k, 3);
            kp[0] = k;
            kp[1] = k >> 1;
            kout[b] = k;
        }
    }
    __syncthreads();
    int k = kp[0], p = kp[1];

    // softmax over tw[d][0..k-1], scattered to wo[b][m][d] with zero padding
    const float* trow = tw + (size_t)tid * KMAXC;
    float mx = -1e30f;
    for (int j = 0; j < k; ++j) mx = fmaxf(mx, trow[j]);
    float s = 0.f;
    for (int j = 0; j < k; ++j) s += expf(trow[j] - mx);
    float inv = 1.0f / s;
    for (int m = 0; m < NM; ++m) {
        int j = m - PP + p;
        float w = (j >= 0 && j < k) ? expf(trow[j] - mx) * inv : 0.f;
        wo[((size_t)b * NM + m) * DD + tid] = w;
    }
}

// ---------------- Kernel 3: depth-wise conv + seasonal ----------------
// grid (L/64, B), block 256. Thread = (d, lsub); computes 32 consecutive l.
// 80-row register window: redundancy 80/32 = 2.5x (was 4x).
__global__ __launch_bounds__(256) void conv_kernel(
    const float* __restrict__ x, const float* __restrict__ wo,
    const int* __restrict__ kin, float* __restrict__ seasonal,
    float* __restrict__ trend) {
    int tid  = threadIdx.x;
    int d    = tid & 127;
    int lsub = tid >> 7;            // 0..1
    int b    = blockIdx.y;
    int l0   = blockIdx.x * 64 + lsub * 32;
    int k    = kin[b];
    int p    = k >> 1;

    const float* xb = x + (size_t)b * LL * DD + d;
    float xwin[80];                 // rows l0-24 .. l0+55
    int r0 = l0 - PP;
    if (r0 >= 0 && r0 + 79 < LL) {  // interior (wave-uniform branch)
#pragma unroll
        for (int i = 0; i < 80; ++i) xwin[i] = xb[(size_t)(r0 + i) * DD];
    } else {
#pragma unroll
        for (int i = 0; i < 80; ++i) {
            int r = r0 + i;
            r = r < 0 ? 0 : (r > LL - 1 ? LL - 1 : r);  // edge clamp (jnp.pad edge)
            xwin[i] = xb[(size_t)r * DD];
        }
    }

    const float* wb = wo + (size_t)b * NM * DD + d;
    float acc[32];
#pragma unroll
    for (int t = 0; t < 32; ++t) acc[t] = 0.f;

#pragma unroll
    for (int c = 0; c < 7; ++c) {
        int mlo = 7 * c;
        // wo[m]==0 outside [PP-p, PP+p]; skip fully-zero chunks (uniform per block)
        if (mlo + 6 < PP - p || mlo > PP + p) continue;
#pragma unroll
        for (int q = 0; q < 7; ++q) {
            int m = 7 * c + q;
            float w = wb[(size_t)m * DD];
#pragma unroll
            for (int t = 0; t < 32; ++t) acc[t] = fmaf(w, xwin[m + t], acc[t]);
        }
    }

    // nontemporal stores: 268 MB write stream, never re-read — keep it out of L3
    // so x (134 MB) stays resident for the conv's own reads.
    float* so = seasonal + ((size_t)b * LL + l0) * DD + d;
    float* to = trend + ((size_t)b * LL + l0) * DD + d;
#pragma unroll
    for (int t = 0; t < 32; ++t) {
        float tr = acc[t];
        __builtin_nontemporal_store(tr, to + (size_t)t * DD);
        __builtin_nontemporal_store(xwin[PP + t] - tr, so + (size_t)t * DD);
    }
}

extern "C" void kernel_launch(void* const* d_in, const int* in_sizes, int n_in,
                              void* d_out, int out_size, void* d_ws, size_t ws_size,
                              hipStream_t stream) {
    const float* x  = (const float*)d_in[0];
    const float* tw = (const float*)d_in[1];
    const float* w1 = (const float*)d_in[2];
    const float* b1 = (const float*)d_in[3];
    const float* w2 = (const float*)d_in[4];
    const float* b2 = (const float*)d_in[5];
    float* outp     = (float*)d_out;
    float* seasonal = outp;
    float* trend    = outp + (size_t)BB * LL * DD;

    float* partial = (float*)d_ws;                         // B*32*D floats = 1 MB
    float* wo      = partial + (size_t)BB * 32 * DD;       // B*49*D floats = 1.53 MB
    int*   kws     = (int*)(wo + (size_t)BB * NM * DD);    // B ints

    colsum_kernel<<<dim3(32, BB), 256, 0, stream>>>(x, partial);
    mlp_weights_kernel<<<BB, 128, 0, stream>>>(partial, tw, w1, b1, w2, b2, wo, kws);
    conv_kernel<<<dim3(LL / 64, BB), 256, 0, stream>>>(x, wo, kws, seasonal, trend);
}